// Round 11
// baseline (2984.270 us; speedup 1.0000x reference)
//
#include <hip/hip_runtime.h>

typedef float f32x4  __attribute__((ext_vector_type(4)));
typedef float f32x16 __attribute__((ext_vector_type(16)));
typedef short short8 __attribute__((ext_vector_type(8)));
typedef int   intx4  __attribute__((ext_vector_type(4)));

#define TT 1024
#define DD 512
#define BTD (32u*1024u*512u)
#define SLOT_SH 16384      // shorts per slot (32KB); 1024 slots, written once each
#define SENTD  0xFF80FF80u

__device__ __forceinline__ unsigned short f2bf(float f){
  unsigned int u = __float_as_uint(f);
  u += 0x7FFFu + ((u >> 16) & 1u);          // round-to-nearest-even
  return (unsigned short)(u >> 16);
}
__device__ __forceinline__ float bf2f(unsigned short s){
  return __uint_as_float(((unsigned)s) << 16);
}
__device__ __forceinline__ float fast_tanh(float x){
  float ax = fabsf(x);
  float e  = __expf(2.0f*ax);
  float r  = 1.0f - 2.0f/(e + 1.0f);
  return x < 0.f ? -r : r;
}
__device__ __forceinline__ unsigned umaxu(unsigned a, unsigned b){ return a > b ? a : b; }

// ---------------- prep: sentinel-fill the 32MB ring ----------------
__global__ void prep_ring_k(uint4* __restrict__ p){
  const size_t n = (size_t)TT * SLOT_SH / 8;
  uint4 s = make_uint4(SENTD, SENTD, SENTD, SENTD);
  for (size_t i = blockIdx.x*(size_t)blockDim.x + threadIdx.x; i < n;
       i += (size_t)gridDim.x*blockDim.x)
    p[i] = s;
}

// ---------------- prep: z, packed weights, d_init (fragment layout) ----------------
__global__ void prep_misc_k(const float* __restrict__ A, const float* __restrict__ noise,
                            const float* __restrict__ Wd, const float* __restrict__ Wz,
                            const float* __restrict__ Wdz, const float* __restrict__ Whd,
                            const float* __restrict__ init_h,
                            unsigned short* __restrict__ zbf, unsigned short* __restrict__ Wu,
                            unsigned short* __restrict__ Wp, unsigned short* __restrict__ Wdzp,
                            unsigned short* __restrict__ dinit){
  const unsigned NZ = 2097152u, NWU = 294912u, NWP = 262144u, NWZ = 65536u, ND = 16384u;
  const unsigned NT = NZ + NWU + NWP + NWZ + ND;
  for (unsigned i = blockIdx.x*blockDim.x + threadIdx.x; i < NT; i += gridDim.x*blockDim.x){
    if (i < NZ){                                   // z = tanh(mu_in_q) + noise*exp(ln_q)
      unsigned m = i >> 6, zi = i & 63u;
      float muin = A[(size_t)m*128u + zi];
      float ln   = A[(size_t)m*128u + 64u + zi];
      zbf[i] = f2bf(fast_tanh(muin) + noise[i]*__expf(ln));
    } else if (i < NZ+NWU){                        // Wu[c][kk]: [Whd | Wz], [512][576]
      unsigned j = i - NZ;
      unsigned c = j / 576u, kk = j - c*576u;
      float v = (kk < 512u) ? Whd[(size_t)c*512u + kk] : Wz[(size_t)c*64u + (kk-512u)];
      Wu[j] = f2bf(v);
    } else if (i < NZ+NWU+NWP){                    // Wp[c][k] = Wd, [512][512]
      unsigned j = i - (NZ+NWU);
      Wp[j] = f2bf(Wd[j]);
    } else if (i < NZ+NWU+NWP+NWZ){                // Wdzp = bf16(Wdz), [128][512]
      unsigned j = i - (NZ+NWU+NWP);
      Wdzp[j] = f2bf(Wdz[j]);
    } else {                                       // d_{-1} = tanh(init_h), fragment layout
      unsigned j = i - (NZ+NWU+NWP+NWZ);
      unsigned b = j >> 9, c = j & 511u;
      unsigned idx = ((c>>4)<<9) + (((c>>3)&1u)<<8) + (b<<3) + (c&7u);
      dinit[idx] = f2bf(fast_tanh(init_h[j]));
    }
  }
}

// ---------------- wnll_init_h -> d_out[BTD] ----------------
__global__ void wnll_k(const float* __restrict__ init_h, const float* __restrict__ mu,
                       float* __restrict__ dout){
  __shared__ float red[256];
  float s = 0.f;
  for (unsigned i = threadIdx.x; i < 16384u; i += 256u){
    float x = init_h[i] - mu[i & 511u];
    s += 0.5f*x*x;
  }
  red[threadIdx.x] = s; __syncthreads();
  for (int st = 128; st > 0; st >>= 1){
    if ((int)threadIdx.x < st) red[threadIdx.x] += red[threadIdx.x + st];
    __syncthreads();
  }
  if (threadIdx.x == 0){
    float nll = (red[0] + 16384.0f*0.91893853320467274f) / 512.0f;
    dout[(size_t)BTD] = 1e-3f * nll;
  }
}

// ---------------- U = (X @ Wu^T + bias)/tau  into d_out (f32) ----------------
__global__ __launch_bounds__(256) void gemm_u_k(
    const float* __restrict__ hd,             // [32768][512] f32
    const unsigned short* __restrict__ Xz,    // [32768][64]  bf16
    const unsigned short* __restrict__ Wu,    // [512][576]   bf16
    const float* __restrict__ bias,
    float* __restrict__ dout)
{
  __shared__ __align__(16) unsigned short Xs[128][40];
  __shared__ __align__(16) unsigned short Ws[128][40];
  const int bm = blockIdx.x >> 2;
  const int bn = blockIdx.x & 3;
  const int tid = threadIdx.x;
  const int lane = tid & 63;
  const int wv = tid >> 6;
  const int m0 = (wv >> 1) * 64, c0 = (wv & 1) * 64;
  f32x4 acc[4][4];
  #pragma unroll
  for (int i=0;i<4;++i)
    #pragma unroll
    for (int j=0;j<4;++j)
      #pragma unroll
      for (int r=0;r<4;++r) acc[i][j][r] = 0.f;

  const int sm = tid >> 1;
  const int sk = (tid & 1) * 16;
  for (int kt = 0; kt < 18; ++kt){
    __syncthreads();
    {
      int mg = bm*128 + sm;
      if (kt < 16){
        const float* src = hd + (size_t)mg*512u + (unsigned)(kt*32 + sk);
        uint2 o[4];
        #pragma unroll
        for (int q=0;q<4;++q){
          f32x4 v = *reinterpret_cast<const f32x4*>(src + 4*q);
          o[q].x = (unsigned)f2bf(v[0]) | ((unsigned)f2bf(v[1])<<16);
          o[q].y = (unsigned)f2bf(v[2]) | ((unsigned)f2bf(v[3])<<16);
        }
        *reinterpret_cast<uint4*>(&Xs[sm][sk])   = make_uint4(o[0].x,o[0].y,o[1].x,o[1].y);
        *reinterpret_cast<uint4*>(&Xs[sm][sk+8]) = make_uint4(o[2].x,o[2].y,o[3].x,o[3].y);
      } else {
        const unsigned short* src = Xz + (size_t)mg*64u + (unsigned)((kt-16)*32 + sk);
        uint4 v0 = *reinterpret_cast<const uint4*>(src);
        uint4 v1 = *reinterpret_cast<const uint4*>(src + 8);
        *reinterpret_cast<uint4*>(&Xs[sm][sk])   = v0;
        *reinterpret_cast<uint4*>(&Xs[sm][sk+8]) = v1;
      }
      int cg = bn*128 + sm;
      const unsigned short* wsrc = Wu + (size_t)cg*576u + (unsigned)(kt*32 + sk);
      uint4 w0 = *reinterpret_cast<const uint4*>(wsrc);
      uint4 w1 = *reinterpret_cast<const uint4*>(wsrc + 8);
      *reinterpret_cast<uint4*>(&Ws[sm][sk])   = w0;
      *reinterpret_cast<uint4*>(&Ws[sm][sk+8]) = w1;
    }
    __syncthreads();
    short8 af[4], bf[4];
    #pragma unroll
    for (int i=0;i<4;++i)
      af[i] = *reinterpret_cast<const short8*>(&Xs[m0 + i*16 + (lane&15)][(lane>>4)*8]);
    #pragma unroll
    for (int j=0;j<4;++j)
      bf[j] = *reinterpret_cast<const short8*>(&Ws[c0 + j*16 + (lane&15)][(lane>>4)*8]);
    #pragma unroll
    for (int i=0;i<4;++i)
      #pragma unroll
      for (int j=0;j<4;++j)
        acc[i][j] = __builtin_amdgcn_mfma_f32_16x16x32_bf16(af[i], bf[j], acc[i][j], 0, 0, 0);
  }
  #pragma unroll
  for (int j=0;j<4;++j){
    int cg = bn*128 + c0 + j*16 + (lane&15);
    float bia  = bias[cg];
    float itau = (cg < 256) ? 0.25f : 0.5f;
    #pragma unroll
    for (int i=0;i<4;++i){
      int mbase = bm*128 + m0 + i*16 + (lane>>4)*4;
      #pragma unroll
      for (int r=0;r<4;++r)
        dout[(size_t)(mbase + r)*512u + cg] = (acc[i][j][r] + bia) * itau;
    }
  }
}

// ---------------- persistent serial recurrence: sentinel-sync, write-once ring ----------------
// grid = 20 WGs x 256.  WG 0..15 (wave 0): D-column workers, 32 cols each.
// WG 16..19 (4 waves): d_seq writers, 16 wave-portions of 2KB per slot.
// Ring: 1024 slots (one per step), each written EXACTLY once -> monotone, no
// reuse, deadlock-free. Valid data dwords < 0xC0000000u (bf16 tanh outputs);
// sentinel 0xFF80FF80. All ring traffic sc0 sc1.
// Round-10: depth-2 speculative gather pipeline. Write-once data makes the
// WAW race on fi benign (a later sample can only overwrite with identical
// final data). Sample k+1 is issued before validating sample k, so the
// sampling interval is ~issue+validate instead of a full L3 round trip.
__global__ __launch_bounds__(256,1) void recur_k(
    float* __restrict__ dout, const float* __restrict__ init_h,
    const unsigned short* __restrict__ Wp, const unsigned short* __restrict__ dinit,
    unsigned short* __restrict__ dcomm)
{
  __shared__ __align__(16) unsigned short tl[32][40];   // transpose block
  const int wg = blockIdx.x;

  // ================= writer WGs (16 waves across 4 WGs) =================
  if (wg >= 16){
    const int tid  = threadIdx.x;
    const int lane = tid & 63;
    const int wid  = (wg - 16)*4 + (tid >> 6);    // 0..15, owns 2KB of each slot
    const int b    = lane & 31;
    const int cb0  = wid*32 + (lane>>5)*8;
    for (int t = 0; t < TT; ++t){
      const char* base = (const char*)dcomm + (size_t)t*32768 + wid*2048 + lane*16;
      intx4 q0, q1;
      for (;;){
        asm volatile(
          "global_load_dwordx4 %0, %2, off sc0 sc1\n\t"
          "global_load_dwordx4 %1, %2, off offset:1024 sc0 sc1\n\t"
          "s_waitcnt vmcnt(0)"
          : "=&v"(q0), "=&v"(q1) : "v"(base) : "memory");
        unsigned mx = umaxu(umaxu(umaxu((unsigned)q0[0],(unsigned)q0[1]),
                                  umaxu((unsigned)q0[2],(unsigned)q0[3])),
                            umaxu(umaxu((unsigned)q1[0],(unsigned)q1[1]),
                                  umaxu((unsigned)q1[2],(unsigned)q1[3])));
        if (__all(mx < 0xC0000000u)) break;
        __builtin_amdgcn_s_sleep(4);   // writers have unbounded slack: back off
      }
      __builtin_amdgcn_sched_barrier(0);
      float* drow = dout + ((size_t)b*TT + t)*DD;
      union { intx4 i; short8 s; } c0, c1; c0.i = q0; c1.i = q1;
      f32x4 o0, o1, o2, o3;
      #pragma unroll
      for (int e=0;e<4;++e){
        o0[e] = bf2f((unsigned short)c0.s[e]);
        o1[e] = bf2f((unsigned short)c0.s[4+e]);
        o2[e] = bf2f((unsigned short)c1.s[e]);
        o3[e] = bf2f((unsigned short)c1.s[4+e]);
      }
      *reinterpret_cast<f32x4*>(drow + cb0)          = o0;
      *reinterpret_cast<f32x4*>(drow + cb0 + 4)      = o1;
      *reinterpret_cast<f32x4*>(drow + cb0 + 16)     = o2;
      *reinterpret_cast<f32x4*>(drow + cb0 + 16 + 4) = o3;
    }
    return;
  }

  // ================= worker WGs (wave 0 only) =================
  if (threadIdx.x >= 64) return;
  const int lane = threadIdx.x;
  const int pc    = wg*32 + (lane & 31);      // D column 0..511
  const int khalf = (lane >> 5) * 8;
  const int bof   = (lane >> 5) * 4;

  short8 wfrag[32];
  #pragma unroll
  for (int kc = 0; kc < 32; ++kc)
    wfrag[kc] = *reinterpret_cast<const short8*>(Wp + (size_t)pc*512u + (unsigned)(kc*16 + khalf));

  const float dec  = (pc < 256) ? 0.75f : 0.5f;
  const float itau = (pc < 256) ? 0.25f : 0.5f;

  float h[16];
  #pragma unroll
  for (int r=0;r<16;++r){
    int b = (r&3) + 8*(r>>2) + bof;
    h[r] = init_h[b*512 + pc];
  }
  float u[16];
  #pragma unroll
  for (int r=0;r<16;++r){
    int b = (r&3) + 8*(r>>2) + bof;
    u[r] = dout[((size_t)b*TT + 0)*DD + pc];
  }

  union CV { intx4 i; short8 s; };

  for (int t = 0; t < TT; ++t){
    const char* gbase = (t == 0)
        ? (const char*)dinit
        : (const char*)dcomm + (size_t)(t-1)*32768;
    const char* base = gbase + lane*16;

    intx4 fi[32];
    // sample 1: fresh defs ("=&v")
    #pragma unroll
    for (int g = 0; g < 8; ++g){
      const char* bp = base + g*4096;
      asm volatile(
        "global_load_dwordx4 %0, %4, off sc0 sc1\n\t"
        "global_load_dwordx4 %1, %4, off offset:1024 sc0 sc1\n\t"
        "global_load_dwordx4 %2, %4, off offset:2048 sc0 sc1\n\t"
        "global_load_dwordx4 %3, %4, off offset:3072 sc0 sc1"
        : "=&v"(fi[4*g]), "=&v"(fi[4*g+1]), "=&v"(fi[4*g+2]), "=&v"(fi[4*g+3])
        : "v"(bp) : "memory");
    }
    // depth-2 standing pipeline: issue sample k+1 ("+v": ties to SAME regs),
    // wait for sample k (vmcnt(32)), validate; repeat until clean.
    for (;;){
      #pragma unroll
      for (int g = 0; g < 8; ++g){
        const char* bp = base + g*4096;
        asm volatile(
          "global_load_dwordx4 %0, %4, off sc0 sc1\n\t"
          "global_load_dwordx4 %1, %4, off offset:1024 sc0 sc1\n\t"
          "global_load_dwordx4 %2, %4, off offset:2048 sc0 sc1\n\t"
          "global_load_dwordx4 %3, %4, off offset:3072 sc0 sc1"
          : "+v"(fi[4*g]), "+v"(fi[4*g+1]), "+v"(fi[4*g+2]), "+v"(fi[4*g+3])
          : "v"(bp) : "memory");
      }
      asm volatile("s_waitcnt vmcnt(32)" ::: "memory");
      __builtin_amdgcn_sched_barrier(0);
      unsigned mx = 0u;
      #pragma unroll
      for (int j=0;j<32;++j){
        mx = umaxu(mx, umaxu(umaxu((unsigned)fi[j][0],(unsigned)fi[j][1]),
                             umaxu((unsigned)fi[j][2],(unsigned)fi[j][3])));
      }
      if (__all(mx < 0xC0000000u)) break;
    }
    // drain the in-flight sample (overwrites with identical write-once data)
    asm volatile("s_waitcnt vmcnt(0)" ::: "memory");
    __builtin_amdgcn_sched_barrier(0);

    // prefetch next-step U (cached; completes during MFMA/tanh/store)
    float un[16];
    if (t+1 < TT){
      #pragma unroll
      for (int r=0;r<16;++r){
        int b = (r&3) + 8*(r>>2) + bof;
        un[r] = dout[((size_t)b*TT + (t+1))*DD + pc];
      }
    }

    // P = d_{t-1} @ W_slice  (two interleaved MFMA chains — round-7 proven codegen)
    f32x16 acc0, acc1;
    #pragma unroll
    for (int q=0;q<16;++q){ acc0[q]=0.f; acc1[q]=0.f; }
    #pragma unroll
    for (int kc=0;kc<16;++kc){
      CV c0, c1; c0.i = fi[2*kc]; c1.i = fi[2*kc+1];
      acc0 = __builtin_amdgcn_mfma_f32_32x32x16_bf16(c0.s, wfrag[2*kc  ], acc0, 0, 0, 0);
      acc1 = __builtin_amdgcn_mfma_f32_32x32x16_bf16(c1.s, wfrag[2*kc+1], acc1, 0, 0, 0);
    }

    // h update + tanh
    float dv[16];
    #pragma unroll
    for (int r=0;r<16;++r){
      float P = acc0[r] + acc1[r];
      h[r]  = dec*h[r] + P*itau + u[r];
      dv[r] = fast_tanh(h[r]);
    }
    // in-wave transpose via LDS: tl[batch][local col]
    #pragma unroll
    for (int r=0;r<16;++r){
      int b = (r&3) + 8*(r>>2) + bof;
      tl[b][lane & 31] = f2bf(dv[r]);
    }
    // two coalesced b128 uncached stores into fragment-layout slot; fire-and-forget
    {
      unsigned short* ds = dcomm + (size_t)t*SLOT_SH + (2*wg)*512 + lane*8;
      short8 s0 = *reinterpret_cast<const short8*>(&tl[lane & 31][khalf]);
      short8 s1 = *reinterpret_cast<const short8*>(&tl[lane & 31][16 + khalf]);
      asm volatile("global_store_dwordx4 %0, %2, off sc0 sc1\n\t"
                   "global_store_dwordx4 %1, %3, off sc0 sc1"
                   :: "v"(ds), "v"(ds + 512), "v"(s0), "v"(s1) : "memory");
    }
    if (t+1 < TT){
      #pragma unroll
      for (int r=0;r<16;++r) u[r] = un[r];
    }
  }
}

// ---------------- epilogue: prior_in = d_shifted @ Wdz^T, fused KL -> atomicAdd ----------------
__global__ __launch_bounds__(256) void gemm_p_k(
    const float* __restrict__ dseq,           // dout: [32][1024][512] f32
    const unsigned short* __restrict__ Wdzp,  // [128][512] bf16
    const float* __restrict__ A,              // [32768][128] f32
    float* __restrict__ dout)
{
  __shared__ __align__(16) unsigned short Xs[128][40];
  __shared__ __align__(16) unsigned short Ws[128][40];
  __shared__ float Ls[128][128];
  __shared__ float red[256];
  const int bm = blockIdx.x;
  const int tid = threadIdx.x;
  const int lane = tid & 63;
  const int wv = tid >> 6;
  const int m0 = (wv >> 1) * 64, c0 = (wv & 1) * 64;
  f32x4 acc[4][4];
  #pragma unroll
  for (int i=0;i<4;++i)
    #pragma unroll
    for (int j=0;j<4;++j)
      #pragma unroll
      for (int r=0;r<4;++r) acc[i][j][r] = 0.f;

  const int sm = tid >> 1;
  const int sk = (tid & 1) * 16;
  for (int kt = 0; kt < 16; ++kt){
    __syncthreads();
    {
      int mg = bm*128 + sm;
      int ttm = mg & 1023;
      int srow = (ttm == 0) ? mg : (mg - 1);       // d[b][t-1]; t==0 rows overridden in KL
      const float* src = dseq + (size_t)srow*512u + (unsigned)(kt*32 + sk);
      uint2 o[4];
      #pragma unroll
      for (int q=0;q<4;++q){
        f32x4 v = *reinterpret_cast<const f32x4*>(src + 4*q);
        o[q].x = (unsigned)f2bf(v[0]) | ((unsigned)f2bf(v[1])<<16);
        o[q].y = (unsigned)f2bf(v[2]) | ((unsigned)f2bf(v[3])<<16);
      }
      *reinterpret_cast<uint4*>(&Xs[sm][sk])   = make_uint4(o[0].x,o[0].y,o[1].x,o[1].y);
      *reinterpret_cast<uint4*>(&Xs[sm][sk+8]) = make_uint4(o[2].x,o[2].y,o[3].x,o[3].y);
      const unsigned short* wsrc = Wdzp + (size_t)sm*512u + (unsigned)(kt*32 + sk);
      uint4 w0 = *reinterpret_cast<const uint4*>(wsrc);
      uint4 w1 = *reinterpret_cast<const uint4*>(wsrc + 8);
      *reinterpret_cast<uint4*>(&Ws[sm][sk])   = w0;
      *reinterpret_cast<uint4*>(&Ws[sm][sk+8]) = w1;
    }
    __syncthreads();
    short8 af[4], bf[4];
    #pragma unroll
    for (int i=0;i<4;++i)
      af[i] = *reinterpret_cast<const short8*>(&Xs[m0 + i*16 + (lane&15)][(lane>>4)*8]);
    #pragma unroll
    for (int j=0;j<4;++j)
      bf[j] = *reinterpret_cast<const short8*>(&Ws[c0 + j*16 + (lane&15)][(lane>>4)*8]);
    #pragma unroll
    for (int i=0;i<4;++i)
      #pragma unroll
      for (int j=0;j<4;++j)
        acc[i][j] = __builtin_amdgcn_mfma_f32_16x16x32_bf16(af[i], bf[j], acc[i][j], 0, 0, 0);
  }
  #pragma unroll
  for (int j=0;j<4;++j){
    int cc = c0 + j*16 + (lane&15);
    #pragma unroll
    for (int i=0;i<4;++i){
      int mm = m0 + i*16 + (lane>>4)*4;
      #pragma unroll
      for (int r=0;r<4;++r)
        Ls[mm + r][cc] = acc[i][j][r];
    }
  }
  __syncthreads();
  float ks = 0.f;
  const int z = tid & 63;
  for (int ml = (tid >> 6); ml < 128; ml += 4){
    int mg = bm*128 + ml;
    int ttm = mg & 1023;
    const float* ap = A + (size_t)mg*128u;
    float mq = fast_tanh(ap[z]);
    float sq = __expf(ap[64 + z]);
    float mp = (ttm == 0) ? 0.f : fast_tanh(Ls[ml][z]);
    float sp = (ttm == 0) ? 1.f : __expf(Ls[ml][64 + z]);
    float dm = mq - mp;
    ks += __logf(sp + 1e-6f) - __logf(sq + 1e-6f) - 0.5f
        + 0.5f*(dm*dm + sq*sq)/(sp*sp + 1e-6f);
  }
  red[tid] = ks; __syncthreads();
  for (int st = 128; st > 0; st >>= 1){
    if (tid < st) red[tid] += red[tid + st];
    __syncthreads();
  }
  if (tid == 0) atomicAdd(dout + (size_t)BTD, red[0] * (1e-3f/64.f));
}

extern "C" void kernel_launch(void* const* d_in, const int* in_sizes, int n_in,
                              void* d_out, int out_size, void* d_ws, size_t ws_size,
                              hipStream_t stream){
  const float* hd        = (const float*)d_in[0];
  const float* A         = (const float*)d_in[1];
  const float* noise     = (const float*)d_in[2];
  const float* Wd        = (const float*)d_in[3];
  const float* Wz        = (const float*)d_in[4];
  const float* Wdz       = (const float*)d_in[5];
  const float* Whd       = (const float*)d_in[6];
  const float* bias      = (const float*)d_in[7];
  const float* init_h    = (const float*)d_in[8];
  const float* init_h_mu = (const float*)d_in[9];
  float* dout = (float*)d_out;

  char* ws = (char*)d_ws;
  unsigned short* z_bf  = (unsigned short*)(ws);                      //  4,194,304 B
  unsigned short* Wu    = (unsigned short*)(ws + 4194304u);           //    589,824 B
  unsigned short* Wp    = (unsigned short*)(ws + 4784128u);           //    524,288 B
  unsigned short* Wdzp  = (unsigned short*)(ws + 5308416u);           //    131,072 B
  unsigned short* dinit = (unsigned short*)(ws + 5439488u);           //     32,768 B
  unsigned short* dcomm = (unsigned short*)(ws + 5472256u);           // 33,554,432 B (1024 slots)

  prep_ring_k<<<2048, 256, 0, stream>>>((uint4*)dcomm);
  prep_misc_k<<<1024, 256, 0, stream>>>(A, noise, Wd, Wz, Wdz, Whd, init_h,
                                        z_bf, Wu, Wp, Wdzp, dinit);
  wnll_k     <<<1,    256, 0, stream>>>(init_h, init_h_mu, dout);
  gemm_u_k   <<<1024, 256, 0, stream>>>(hd, z_bf, Wu, bias, dout);
  recur_k    <<<20,   256, 0, stream>>>(dout, init_h, Wp, dinit, dcomm);
  gemm_p_k   <<<256,  256, 0, stream>>>(dout, Wdzp, A, dout);
}

// Round 12
// 2248.604 us; speedup vs baseline: 1.3272x; 1.3272x over previous
//
#include <hip/hip_runtime.h>

typedef float f32x4  __attribute__((ext_vector_type(4)));
typedef short short8 __attribute__((ext_vector_type(8)));
typedef int   intx4  __attribute__((ext_vector_type(4)));

#define TT 1024
#define DD 512
#define BTD (32u*1024u*512u)
#define GSLOT_SH 8192      // shorts per group slot (16KB); 2 groups x 1024 slots, write-once
#define GRING_SH (1024u*8192u)   // shorts per group ring (16MB)
#define SENTD  0xFF80FF80u

__device__ __forceinline__ unsigned short f2bf(float f){
  unsigned int u = __float_as_uint(f);
  u += 0x7FFFu + ((u >> 16) & 1u);          // round-to-nearest-even
  return (unsigned short)(u >> 16);
}
__device__ __forceinline__ float bf2f(unsigned short s){
  return __uint_as_float(((unsigned)s) << 16);
}
__device__ __forceinline__ float fast_tanh(float x){
  float ax = fabsf(x);
  float e  = __expf(2.0f*ax);
  float r  = 1.0f - 2.0f/(e + 1.0f);
  return x < 0.f ? -r : r;
}
__device__ __forceinline__ unsigned umaxu(unsigned a, unsigned b){ return a > b ? a : b; }

// ---------------- prep: sentinel-fill the 32MB ring ----------------
__global__ void prep_ring_k(uint4* __restrict__ p){
  const size_t n = (size_t)2 * GRING_SH / 8;
  uint4 s = make_uint4(SENTD, SENTD, SENTD, SENTD);
  for (size_t i = blockIdx.x*(size_t)blockDim.x + threadIdx.x; i < n;
       i += (size_t)gridDim.x*blockDim.x)
    p[i] = s;
}

// ---------------- prep: z, packed weights, d_init (per-group M=16 frag layout) ----------------
__global__ void prep_misc_k(const float* __restrict__ A, const float* __restrict__ noise,
                            const float* __restrict__ Wd, const float* __restrict__ Wz,
                            const float* __restrict__ Wdz, const float* __restrict__ Whd,
                            const float* __restrict__ init_h,
                            unsigned short* __restrict__ zbf, unsigned short* __restrict__ Wu,
                            unsigned short* __restrict__ Wp, unsigned short* __restrict__ Wdzp,
                            unsigned short* __restrict__ dinit){
  const unsigned NZ = 2097152u, NWU = 294912u, NWP = 262144u, NWZ = 65536u, ND = 16384u;
  const unsigned NT = NZ + NWU + NWP + NWZ + ND;
  for (unsigned i = blockIdx.x*blockDim.x + threadIdx.x; i < NT; i += gridDim.x*blockDim.x){
    if (i < NZ){                                   // z = tanh(mu_in_q) + noise*exp(ln_q)
      unsigned m = i >> 6, zi = i & 63u;
      float muin = A[(size_t)m*128u + zi];
      float ln   = A[(size_t)m*128u + 64u + zi];
      zbf[i] = f2bf(fast_tanh(muin) + noise[i]*__expf(ln));
    } else if (i < NZ+NWU){                        // Wu[c][kk]: [Whd | Wz], [512][576]
      unsigned j = i - NZ;
      unsigned c = j / 576u, kk = j - c*576u;
      float v = (kk < 512u) ? Whd[(size_t)c*512u + kk] : Wz[(size_t)c*64u + (kk-512u)];
      Wu[j] = f2bf(v);
    } else if (i < NZ+NWU+NWP){                    // Wp[c][k] = Wd, [512][512]
      unsigned j = i - (NZ+NWU);
      Wp[j] = f2bf(Wd[j]);
    } else if (i < NZ+NWU+NWP+NWZ){                // Wdzp = bf16(Wdz), [128][512]
      unsigned j = i - (NZ+NWU+NWP);
      Wdzp[j] = f2bf(Wdz[j]);
    } else {                                       // d_{-1}: per-group M=16 A-frag layout
      unsigned j = i - (NZ+NWU+NWP+NWZ);           // 0..16383
      unsigned g   = j >> 13;                      // group
      unsigned rem = j & 8191u;
      unsigned kt  = rem >> 9;                     // k-tile (512 shorts each)
      unsigned li  = (rem & 511u) >> 3;            // lane
      unsigned e   = rem & 7u;
      unsigned row = li & 15u;
      unsigned col = kt*32u + (li >> 4)*8u + e;
      unsigned b   = g*16u + row;
      dinit[j] = f2bf(fast_tanh(init_h[(size_t)b*512u + col]));
    }
  }
}

// ---------------- wnll_init_h -> d_out[BTD] ----------------
__global__ void wnll_k(const float* __restrict__ init_h, const float* __restrict__ mu,
                       float* __restrict__ dout){
  __shared__ float red[256];
  float s = 0.f;
  for (unsigned i = threadIdx.x; i < 16384u; i += 256u){
    float x = init_h[i] - mu[i & 511u];
    s += 0.5f*x*x;
  }
  red[threadIdx.x] = s; __syncthreads();
  for (int st = 128; st > 0; st >>= 1){
    if ((int)threadIdx.x < st) red[threadIdx.x] += red[threadIdx.x + st];
    __syncthreads();
  }
  if (threadIdx.x == 0){
    float nll = (red[0] + 16384.0f*0.91893853320467274f) / 512.0f;
    dout[(size_t)BTD] = 1e-3f * nll;
  }
}

// ---------------- U = (X @ Wu^T + bias)/tau  into d_out (f32) ----------------
__global__ __launch_bounds__(256) void gemm_u_k(
    const float* __restrict__ hd,             // [32768][512] f32
    const unsigned short* __restrict__ Xz,    // [32768][64]  bf16
    const unsigned short* __restrict__ Wu,    // [512][576]   bf16
    const float* __restrict__ bias,
    float* __restrict__ dout)
{
  __shared__ __align__(16) unsigned short Xs[128][40];
  __shared__ __align__(16) unsigned short Ws[128][40];
  const int bm = blockIdx.x >> 2;
  const int bn = blockIdx.x & 3;
  const int tid = threadIdx.x;
  const int lane = tid & 63;
  const int wv = tid >> 6;
  const int m0 = (wv >> 1) * 64, c0 = (wv & 1) * 64;
  f32x4 acc[4][4];
  #pragma unroll
  for (int i=0;i<4;++i)
    #pragma unroll
    for (int j=0;j<4;++j)
      #pragma unroll
      for (int r=0;r<4;++r) acc[i][j][r] = 0.f;

  const int sm = tid >> 1;
  const int sk = (tid & 1) * 16;
  for (int kt = 0; kt < 18; ++kt){
    __syncthreads();
    {
      int mg = bm*128 + sm;
      if (kt < 16){
        const float* src = hd + (size_t)mg*512u + (unsigned)(kt*32 + sk);
        uint2 o[4];
        #pragma unroll
        for (int q=0;q<4;++q){
          f32x4 v = *reinterpret_cast<const f32x4*>(src + 4*q);
          o[q].x = (unsigned)f2bf(v[0]) | ((unsigned)f2bf(v[1])<<16);
          o[q].y = (unsigned)f2bf(v[2]) | ((unsigned)f2bf(v[3])<<16);
        }
        *reinterpret_cast<uint4*>(&Xs[sm][sk])   = make_uint4(o[0].x,o[0].y,o[1].x,o[1].y);
        *reinterpret_cast<uint4*>(&Xs[sm][sk+8]) = make_uint4(o[2].x,o[2].y,o[3].x,o[3].y);
      } else {
        const unsigned short* src = Xz + (size_t)mg*64u + (unsigned)((kt-16)*32 + sk);
        uint4 v0 = *reinterpret_cast<const uint4*>(src);
        uint4 v1 = *reinterpret_cast<const uint4*>(src + 8);
        *reinterpret_cast<uint4*>(&Xs[sm][sk])   = v0;
        *reinterpret_cast<uint4*>(&Xs[sm][sk+8]) = v1;
      }
      int cg = bn*128 + sm;
      const unsigned short* wsrc = Wu + (size_t)cg*576u + (unsigned)(kt*32 + sk);
      uint4 w0 = *reinterpret_cast<const uint4*>(wsrc);
      uint4 w1 = *reinterpret_cast<const uint4*>(wsrc + 8);
      *reinterpret_cast<uint4*>(&Ws[sm][sk])   = w0;
      *reinterpret_cast<uint4*>(&Ws[sm][sk+8]) = w1;
    }
    __syncthreads();
    short8 af[4], bf[4];
    #pragma unroll
    for (int i=0;i<4;++i)
      af[i] = *reinterpret_cast<const short8*>(&Xs[m0 + i*16 + (lane&15)][(lane>>4)*8]);
    #pragma unroll
    for (int j=0;j<4;++j)
      bf[j] = *reinterpret_cast<const short8*>(&Ws[c0 + j*16 + (lane&15)][(lane>>4)*8]);
    #pragma unroll
    for (int i=0;i<4;++i)
      #pragma unroll
      for (int j=0;j<4;++j)
        acc[i][j] = __builtin_amdgcn_mfma_f32_16x16x32_bf16(af[i], bf[j], acc[i][j], 0, 0, 0);
  }
  #pragma unroll
  for (int j=0;j<4;++j){
    int cg = bn*128 + c0 + j*16 + (lane&15);
    float bia  = bias[cg];
    float itau = (cg < 256) ? 0.25f : 0.5f;
    #pragma unroll
    for (int i=0;i<4;++i){
      int mbase = bm*128 + m0 + i*16 + (lane>>4)*4;
      #pragma unroll
      for (int r=0;r<4;++r)
        dout[(size_t)(mbase + r)*512u + cg] = (acc[i][j][r] + bia) * itau;
    }
  }
}

// ---------------- persistent serial recurrence: 2 independent batch groups ----------------
// grid = 32 WGs x 64.  WG = (g = wg>>4, wl = wg&15): group g (batch rows 16g..16g+16),
// column slice [32*wl, 32*wl+32).  M=16 MFMA 16x16x32.  Each group has its own
// write-once 1024-slot ring (16KB slots, A-frag layout) -> groups fully decoupled.
// No writer WGs: d_seq expansion is a post-pass (expand_k).
// Protocol: valid dwords < 0xC0000000u (bf16 tanh pairs); sentinel 0xFF80FF80;
// depth-2 speculative gather pipeline (write-once => register WAW is benign).
__global__ __launch_bounds__(64,1) void recur_k(
    const float* __restrict__ uin, const float* __restrict__ init_h,
    const unsigned short* __restrict__ Wp, const unsigned short* __restrict__ dinit,
    unsigned short* __restrict__ dcomm)
{
  __shared__ __align__(16) unsigned short tl[16][32];   // transpose block (1KB)
  const int wg   = blockIdx.x;
  const int g    = wg >> 4;
  const int wl   = wg & 15;
  const int lane = threadIdx.x;
  const int l4   = lane >> 4;     // 0..3
  const int c16  = lane & 15;

  // B-frags resident in VGPRs: wfrag[n][k] = W[col][k*32 + l4*8 ..], col = wl*32+n*16+c16
  short8 wfrag[2][16];
  #pragma unroll
  for (int n = 0; n < 2; ++n)
    #pragma unroll
    for (int k = 0; k < 16; ++k)
      wfrag[n][k] = *reinterpret_cast<const short8*>(
          Wp + (size_t)(wl*32 + n*16 + c16)*512u + (unsigned)(k*32 + l4*8));

  const float dec  = (wl < 8) ? 0.75f : 0.5f;   // cols [0,256) vs [256,512): uniform per WG
  const float itau = (wl < 8) ? 0.25f : 0.5f;

  // h,u: n in {0,1} (col = wl*32+n*16+c16), r in 0..3 (batch b = 16g + l4*4 + r)
  float h[2][4], u[2][4];
  #pragma unroll
  for (int n = 0; n < 2; ++n){
    int col = wl*32 + n*16 + c16;
    #pragma unroll
    for (int r = 0; r < 4; ++r){
      int b = 16*g + l4*4 + r;
      h[n][r] = init_h[(size_t)b*512u + col];
      u[n][r] = uin[((size_t)b*TT + 0)*DD + col];
    }
  }

  unsigned short* ring = dcomm + (size_t)g*GRING_SH;
  union CV { intx4 i; short8 s; };

  for (int t = 0; t < TT; ++t){
    const char* base = (t == 0)
        ? (const char*)(dinit + g*8192) + lane*16
        : (const char*)(ring + (size_t)(t-1)*GSLOT_SH) + lane*16;

    intx4 fi[16];
    // sample 1: fresh defs
    #pragma unroll
    for (int q = 0; q < 4; ++q){
      const char* bp = base + q*4096;
      asm volatile(
        "global_load_dwordx4 %0, %4, off sc0 sc1\n\t"
        "global_load_dwordx4 %1, %4, off offset:1024 sc0 sc1\n\t"
        "global_load_dwordx4 %2, %4, off offset:2048 sc0 sc1\n\t"
        "global_load_dwordx4 %3, %4, off offset:3072 sc0 sc1"
        : "=&v"(fi[4*q]), "=&v"(fi[4*q+1]), "=&v"(fi[4*q+2]), "=&v"(fi[4*q+3])
        : "v"(bp) : "memory");
    }
    // depth-2 standing pipeline: issue sample k+1 into the SAME regs, wait for
    // sample k (vmcnt(16)), validate; repeat until clean.
    for (;;){
      #pragma unroll
      for (int q = 0; q < 4; ++q){
        const char* bp = base + q*4096;
        asm volatile(
          "global_load_dwordx4 %0, %4, off sc0 sc1\n\t"
          "global_load_dwordx4 %1, %4, off offset:1024 sc0 sc1\n\t"
          "global_load_dwordx4 %2, %4, off offset:2048 sc0 sc1\n\t"
          "global_load_dwordx4 %3, %4, off offset:3072 sc0 sc1"
          : "+v"(fi[4*q]), "+v"(fi[4*q+1]), "+v"(fi[4*q+2]), "+v"(fi[4*q+3])
          : "v"(bp) : "memory");
      }
      asm volatile("s_waitcnt vmcnt(16)" ::: "memory");
      __builtin_amdgcn_sched_barrier(0);
      unsigned mx = 0u;
      #pragma unroll
      for (int j=0;j<16;++j){
        mx = umaxu(mx, umaxu(umaxu((unsigned)fi[j][0],(unsigned)fi[j][1]),
                             umaxu((unsigned)fi[j][2],(unsigned)fi[j][3])));
      }
      if (__all(mx < 0xC0000000u)) break;
    }
    asm volatile("s_waitcnt vmcnt(0)" ::: "memory");   // drain in-flight sample (idempotent)
    __builtin_amdgcn_sched_barrier(0);

    // prefetch next-step U (cached; completes under MFMA/tanh/store)
    float un[2][4];
    if (t+1 < TT){
      #pragma unroll
      for (int n = 0; n < 2; ++n){
        int col = wl*32 + n*16 + c16;
        #pragma unroll
        for (int r = 0; r < 4; ++r){
          int b = 16*g + l4*4 + r;
          un[n][r] = uin[((size_t)b*TT + (t+1))*DD + col];
        }
      }
    }

    // P = d_{t-1} @ W_slice : two interleaved 16-deep MFMA chains (one per N-tile)
    f32x4 acc0, acc1;
    #pragma unroll
    for (int q=0;q<4;++q){ acc0[q]=0.f; acc1[q]=0.f; }
    #pragma unroll
    for (int k = 0; k < 16; ++k){
      CV cv; cv.i = fi[k];
      acc0 = __builtin_amdgcn_mfma_f32_16x16x32_bf16(cv.s, wfrag[0][k], acc0, 0, 0, 0);
      acc1 = __builtin_amdgcn_mfma_f32_16x16x32_bf16(cv.s, wfrag[1][k], acc1, 0, 0, 0);
    }

    // h update + tanh.  C-layout: lane holds P[row=l4*4+r][col=n*16+c16]
    float dv[2][4];
    #pragma unroll
    for (int r = 0; r < 4; ++r){
      h[0][r] = dec*h[0][r] + acc0[r]*itau + u[0][r];
      h[1][r] = dec*h[1][r] + acc1[r]*itau + u[1][r];
      dv[0][r] = fast_tanh(h[0][r]);
      dv[1][r] = fast_tanh(h[1][r]);
    }
    // in-wave transpose via LDS to A-frag layout
    #pragma unroll
    for (int n = 0; n < 2; ++n)
      #pragma unroll
      for (int r = 0; r < 4; ++r)
        tl[l4*4 + r][n*16 + c16] = f2bf(dv[n][r]);
    // one coalesced b128 uncached store into this WG's k-tile region; fire-and-forget
    {
      short8 sv = *reinterpret_cast<const short8*>(&tl[c16][l4*8]);
      unsigned short* ds = ring + (size_t)t*GSLOT_SH + wl*512 + lane*8;
      asm volatile("global_store_dwordx4 %0, %1, off sc0 sc1"
                   :: "v"(ds), "v"(sv) : "memory");
    }
    if (t+1 < TT){
      #pragma unroll
      for (int n = 0; n < 2; ++n)
        #pragma unroll
        for (int r = 0; r < 4; ++r) u[n][r] = un[n][r];
    }
  }
}

// ---------------- post-pass: expand ring (bf16 frag) -> d_seq (f32) ----------------
__global__ __launch_bounds__(256) void expand_k(const unsigned short* __restrict__ dcomm,
                                                float* __restrict__ dout){
  __shared__ unsigned short sl[8192];
  const int bid = blockIdx.x;            // 0..2047
  const int t = bid >> 1, g = bid & 1;
  const unsigned short* src = dcomm + (size_t)g*GRING_SH + (size_t)t*GSLOT_SH;
  const int tid = threadIdx.x;
  #pragma unroll
  for (int it = 0; it < 4; ++it){
    int o = it*2048 + tid*8;
    *reinterpret_cast<short8*>(&sl[o]) = *reinterpret_cast<const short8*>(src + o);
  }
  __syncthreads();
  const int row  = tid >> 4;             // 0..15
  const int colb = (tid & 15) * 32;      // one full k-tile per thread
  const int kt   = colb >> 5;
  const int b    = g*16 + row;
  float* drow = dout + ((size_t)b*TT + t)*DD + colb;
  #pragma unroll
  for (int hi = 0; hi < 4; ++hi){
    const unsigned short* p = &sl[kt*512 + (hi*16 + row)*8];
    f32x4 o0, o1;
    #pragma unroll
    for (int e = 0; e < 4; ++e){
      o0[e] = bf2f(p[e]);
      o1[e] = bf2f(p[4+e]);
    }
    *reinterpret_cast<f32x4*>(drow + hi*8)     = o0;
    *reinterpret_cast<f32x4*>(drow + hi*8 + 4) = o1;
  }
}

// ---------------- epilogue: prior_in = d_shifted @ Wdz^T, fused KL -> atomicAdd ----------------
__global__ __launch_bounds__(256) void gemm_p_k(
    const float* __restrict__ dseq,           // dout: [32][1024][512] f32
    const unsigned short* __restrict__ Wdzp,  // [128][512] bf16
    const float* __restrict__ A,              // [32768][128] f32
    float* __restrict__ dout)
{
  __shared__ __align__(16) unsigned short Xs[128][40];
  __shared__ __align__(16) unsigned short Ws[128][40];
  __shared__ float Ls[128][128];
  __shared__ float red[256];
  const int bm = blockIdx.x;
  const int tid = threadIdx.x;
  const int lane = tid & 63;
  const int wv = tid >> 6;
  const int m0 = (wv >> 1) * 64, c0 = (wv & 1) * 64;
  f32x4 acc[4][4];
  #pragma unroll
  for (int i=0;i<4;++i)
    #pragma unroll
    for (int j=0;j<4;++j)
      #pragma unroll
      for (int r=0;r<4;++r) acc[i][j][r] = 0.f;

  const int sm = tid >> 1;
  const int sk = (tid & 1) * 16;
  for (int kt = 0; kt < 16; ++kt){
    __syncthreads();
    {
      int mg = bm*128 + sm;
      int ttm = mg & 1023;
      int srow = (ttm == 0) ? mg : (mg - 1);       // d[b][t-1]; t==0 rows overridden in KL
      const float* src = dseq + (size_t)srow*512u + (unsigned)(kt*32 + sk);
      uint2 o[4];
      #pragma unroll
      for (int q=0;q<4;++q){
        f32x4 v = *reinterpret_cast<const f32x4*>(src + 4*q);
        o[q].x = (unsigned)f2bf(v[0]) | ((unsigned)f2bf(v[1])<<16);
        o[q].y = (unsigned)f2bf(v[2]) | ((unsigned)f2bf(v[3])<<16);
      }
      *reinterpret_cast<uint4*>(&Xs[sm][sk])   = make_uint4(o[0].x,o[0].y,o[1].x,o[1].y);
      *reinterpret_cast<uint4*>(&Xs[sm][sk+8]) = make_uint4(o[2].x,o[2].y,o[3].x,o[3].y);
      const unsigned short* wsrc = Wdzp + (size_t)sm*512u + (unsigned)(kt*32 + sk);
      uint4 w0 = *reinterpret_cast<const uint4*>(wsrc);
      uint4 w1 = *reinterpret_cast<const uint4*>(wsrc + 8);
      *reinterpret_cast<uint4*>(&Ws[sm][sk])   = w0;
      *reinterpret_cast<uint4*>(&Ws[sm][sk+8]) = w1;
    }
    __syncthreads();
    short8 af[4], bf[4];
    #pragma unroll
    for (int i=0;i<4;++i)
      af[i] = *reinterpret_cast<const short8*>(&Xs[m0 + i*16 + (lane&15)][(lane>>4)*8]);
    #pragma unroll
    for (int j=0;j<4;++j)
      bf[j] = *reinterpret_cast<const short8*>(&Ws[c0 + j*16 + (lane&15)][(lane>>4)*8]);
    #pragma unroll
    for (int i=0;i<4;++i)
      #pragma unroll
      for (int j=0;j<4;++j)
        acc[i][j] = __builtin_amdgcn_mfma_f32_16x16x32_bf16(af[i], bf[j], acc[i][j], 0, 0, 0);
  }
  #pragma unroll
  for (int j=0;j<4;++j){
    int cc = c0 + j*16 + (lane&15);
    #pragma unroll
    for (int i=0;i<4;++i){
      int mm = m0 + i*16 + (lane>>4)*4;
      #pragma unroll
      for (int r=0;r<4;++r)
        Ls[mm + r][cc] = acc[i][j][r];
    }
  }
  __syncthreads();
  float ks = 0.f;
  const int z = tid & 63;
  for (int ml = (tid >> 6); ml < 128; ml += 4){
    int mg = bm*128 + ml;
    int ttm = mg & 1023;
    const float* ap = A + (size_t)mg*128u;
    float mq = fast_tanh(ap[z]);
    float sq = __expf(ap[64 + z]);
    float mp = (ttm == 0) ? 0.f : fast_tanh(Ls[ml][z]);
    float sp = (ttm == 0) ? 1.f : __expf(Ls[ml][64 + z]);
    float dm = mq - mp;
    ks += __logf(sp + 1e-6f) - __logf(sq + 1e-6f) - 0.5f
        + 0.5f*(dm*dm + sq*sq)/(sp*sp + 1e-6f);
  }
  red[tid] = ks; __syncthreads();
  for (int st = 128; st > 0; st >>= 1){
    if (tid < st) red[tid] += red[tid + st];
    __syncthreads();
  }
  if (tid == 0) atomicAdd(dout + (size_t)BTD, red[0] * (1e-3f/64.f));
}

extern "C" void kernel_launch(void* const* d_in, const int* in_sizes, int n_in,
                              void* d_out, int out_size, void* d_ws, size_t ws_size,
                              hipStream_t stream){
  const float* hd        = (const float*)d_in[0];
  const float* A         = (const float*)d_in[1];
  const float* noise     = (const float*)d_in[2];
  const float* Wd        = (const float*)d_in[3];
  const float* Wz        = (const float*)d_in[4];
  const float* Wdz       = (const float*)d_in[5];
  const float* Whd       = (const float*)d_in[6];
  const float* bias      = (const float*)d_in[7];
  const float* init_h    = (const float*)d_in[8];
  const float* init_h_mu = (const float*)d_in[9];
  float* dout = (float*)d_out;

  char* ws = (char*)d_ws;
  unsigned short* z_bf  = (unsigned short*)(ws);                      //  4,194,304 B
  unsigned short* Wu    = (unsigned short*)(ws + 4194304u);           //    589,824 B
  unsigned short* Wp    = (unsigned short*)(ws + 4784128u);           //    524,288 B
  unsigned short* Wdzp  = (unsigned short*)(ws + 5308416u);           //    131,072 B
  unsigned short* dinit = (unsigned short*)(ws + 5439488u);           //     32,768 B
  unsigned short* dcomm = (unsigned short*)(ws + 5472256u);           // 33,554,432 B (2 rings)

  prep_ring_k<<<2048, 256, 0, stream>>>((uint4*)dcomm);
  prep_misc_k<<<1024, 256, 0, stream>>>(A, noise, Wd, Wz, Wdz, Whd, init_h,
                                        z_bf, Wu, Wp, Wdzp, dinit);
  wnll_k     <<<1,    256, 0, stream>>>(init_h, init_h_mu, dout);
  gemm_u_k   <<<1024, 256, 0, stream>>>(hd, z_bf, Wu, bias, dout);
  recur_k    <<<32,    64, 0, stream>>>(dout, init_h, Wp, dinit, dcomm);
  expand_k   <<<2048, 256, 0, stream>>>(dcomm, dout);
  gemm_p_k   <<<256,  256, 0, stream>>>(dout, Wdzp, A, dout);
}